// Round 2
// baseline (371.185 us; speedup 1.0000x reference)
//
#include <hip/hip_runtime.h>
#include <hip/hip_bf16.h>

// Problem constants
#define BATCH   65536
#define HW      28
#define OHW     26
#define FEAT    676      // 26*26
#define HID     200
#define NCLS    10
#define MT      16       // images per conv block
#define NBLOCKS (BATCH / MT)    // 4096
#define MT2     64       // images per gemm block (4 m-tiles)
#define GBLOCKS (BATCH / MT2)   // 1024

typedef __attribute__((ext_vector_type(8))) __bf16 bf16x8;
typedef __attribute__((ext_vector_type(4))) float  f32x4;

__device__ __forceinline__ unsigned int pk2(float a, float b) {
  __hip_bfloat16 ha = __float2bfloat16(a), hb = __float2bfloat16(b);
  return (unsigned int)__builtin_bit_cast(unsigned short, ha)
       | ((unsigned int)__builtin_bit_cast(unsigned short, hb) << 16);
}

// ---------------------------------------------------------------------------
// A-fragment layout (XOR-swizzled), used for feat (LDS + global) and hidA:
//   element (m, k) lives at ((k>>5)*64 + ((k>>3)&3)*16 + (m ^ ((k>>5)&7)))*8 + (k&7)
// GEMM read for lane at K-chunk kc: base + (kc*64 + (lane ^ (kc&7)))*8
//   -> lane l holds row m=l&15, k=kc*32+(l>>4)*8+j.  64 distinct contiguous
//   16B chunks per wave = conflict-free in LDS, same-1KB-segment in global.
// ---------------------------------------------------------------------------
__device__ __forceinline__ unsigned short* fslot(unsigned short* base, int m, int k) {
  const int kc = k >> 5;
  return base + ((kc * 64 + ((k >> 3) & 3) * 16 + (m ^ (kc & 7))) * 8) + (k & 7);
}

// ---------------------------------------------------------------------------
// prep_w1tf: w1 (676x200 f32) -> bf16 B-fragment order. One thread per 16B
// output chunk (vectorized stores; reads coalesce across ln).
// chunk c = (kc*13+nt)*64 + qd*16 + ln ; holds j=0..7 of k=kc*32+qd*8+j,
// n = nt*16+ln (zero-padded).
// ---------------------------------------------------------------------------
__global__ __launch_bounds__(256) void prep_w1tf(const float* __restrict__ w1,
                                                 unsigned short* __restrict__ w1tf) {
  int c = blockIdx.x * 256 + threadIdx.x;
  if (c >= 22 * 13 * 64) return;
  int ln = c & 15;
  int qd = (c >> 4) & 3;
  int g  = c >> 6;                 // kc*13 + nt
  int kc = g / 13, nt = g - kc * 13;
  int n  = nt * 16 + ln;
  float v[8];
  #pragma unroll
  for (int j = 0; j < 8; ++j) {
    int k = kc * 32 + qd * 8 + j;
    v[j] = (k < FEAT && n < HID) ? w1[k * HID + n] : 0.f;
  }
  uint4 o = make_uint4(pk2(v[0], v[1]), pk2(v[2], v[3]),
                       pk2(v[4], v[5]), pk2(v[6], v[7]));
  *(uint4*)(w1tf + (size_t)c * 8) = o;
}

// w2 (200x10 f32) -> bf16 B-fragment order, K=224 N=16 padded. 7 KB.
__global__ __launch_bounds__(256) void prep_w2f(const float* __restrict__ w2,
                                                unsigned short* __restrict__ w2f) {
  int c = blockIdx.x * 256 + threadIdx.x;
  if (c >= 7 * 64) return;
  int lane = c & 63, kc = c >> 6;
  int col = lane & 15;
  float v[8];
  #pragma unroll
  for (int j = 0; j < 8; ++j) {
    int k = kc * 32 + (lane >> 4) * 8 + j;
    v[j] = (col < NCLS && k < HID) ? w2[k * NCLS + col] : 0.f;
  }
  uint4 o = make_uint4(pk2(v[0], v[1]), pk2(v[2], v[3]),
                       pk2(v[4], v[5]), pk2(v[6], v[7]));
  *(uint4*)(w2f + (size_t)c * 8) = o;
}

// ---------------------------------------------------------------------------
// convk: conv -> feat in fragment layout, staged in LDS, coalesced copy-out.
// featg block b (images 16b..16b+15) = 22,528 B at featg + b*11264 shorts.
// ---------------------------------------------------------------------------
__global__ __launch_bounds__(256) void convk(const float* __restrict__ x,
                                             const float* __restrict__ cwp,
                                             unsigned short* __restrict__ featg) {
  __shared__ __align__(16) unsigned short featA[22 * 64 * 8];  // 22,528 B
  const int tid  = threadIdx.x;
  const int wave = tid >> 6;
  const int lane = tid & 63;

  // zero feat K-pad (k=676..703), all 16 rows
  for (int i = tid; i < MT * 14; i += 256) {
    int m = i / 14, d = i - m * 14;
    *(unsigned int*)fslot(featA, m, 676 + 2 * d) = 0u;
  }

  float cw[9];
  #pragma unroll
  for (int t = 0; t < 9; ++t) cw[t] = cwp[t];

  const float* xb = x + (size_t)blockIdx.x * (MT * 784);
  for (int t0 = 0; t0 < 364; t0 += 64) {
    const int t = t0 + lane;
    if (t < 364) {
      const int p   = (t * 721) >> 16;        // t / 91
      const int r91 = t - 91 * p;
      const int iq  = (r91 * 9363) >> 16;     // r91 / 7
      const int jc  = r91 - 7 * iq;
      const int m   = 4 * p + wave;
      const float* xw = xb + m * 784;
      float in[4][6];
      const int c2 = (jc < 6) ? 4 : 2;        // jc==6: re-read cols 26,27, no OOB
      #pragma unroll
      for (int rr = 0; rr < 4; ++rr) {
        const float* rp = xw + (2 * iq + rr) * HW + 4 * jc;   // 16B aligned
        const float4 v = *(const float4*)rp;
        const float2 u = *(const float2*)(rp + c2);           // 8B aligned
        in[rr][0] = v.x; in[rr][1] = v.y; in[rr][2] = v.z; in[rr][3] = v.w;
        in[rr][4] = u.x; in[rr][5] = u.y;
      }
      float o[2][4];
      #pragma unroll
      for (int dr = 0; dr < 2; ++dr)
        #pragma unroll
        for (int dc = 0; dc < 4; ++dc) {
          float s = 0.f;
          #pragma unroll
          for (int di = 0; di < 3; ++di)
            #pragma unroll
            for (int dj = 0; dj < 3; ++dj)
              s += cw[di * 3 + dj] * in[dr + di][dc + dj];
          o[dr][dc] = s;
        }
      const int k0 = 52 * iq + 4 * jc;        // k0 % 4 == 0
      if (jc < 6) {
        *(uint2*)fslot(featA, m, k0) =
            make_uint2(pk2(o[0][0], o[0][1]), pk2(o[0][2], o[0][3]));
        *(unsigned int*)fslot(featA, m, k0 + OHW)     = pk2(o[1][0], o[1][1]);
        *(unsigned int*)fslot(featA, m, k0 + OHW + 2) = pk2(o[1][2], o[1][3]);
      } else {                                // cols 24,25 only
        *(unsigned int*)fslot(featA, m, k0)       = pk2(o[0][0], o[0][1]);
        *(unsigned int*)fslot(featA, m, k0 + OHW) = pk2(o[1][0], o[1][1]);
      }
    }
  }
  __syncthreads();

  // coalesced copy-out: 1408 x 16B
  const uint4* src = (const uint4*)featA;
  uint4* dst = (uint4*)(featg + (size_t)blockIdx.x * (22 * 64 * 8));
  for (int i = tid; i < 1408; i += 256) dst[i] = src[i];
}

// ---------------------------------------------------------------------------
// gemmk: block = 64 images (4 m-tiles). Per wave: NT n-tiles, b reused across
// 4 m-tiles -> 16 MFMA per K-chunk, 64-acc ILP. a straight from global featg.
// ---------------------------------------------------------------------------
template<int NT0, int NT>
__device__ __forceinline__ void gemmB_slice(
    const unsigned short* __restrict__ featg, const unsigned short* __restrict__ w1tf,
    const float* __restrict__ b1, unsigned short* hidA, int lane, int blk4) {
  const int ln = lane & 15, qd = lane >> 4;
  f32x4 acc[4][NT];
  #pragma unroll
  for (int mi = 0; mi < 4; ++mi)
    #pragma unroll
    for (int t = 0; t < NT; ++t) acc[mi][t] = (f32x4){0.f, 0.f, 0.f, 0.f};

  for (int kc = 0; kc < 22; ++kc) {
    const int sw = lane ^ (kc & 7);
    bf16x8 b[NT];
    #pragma unroll
    for (int t = 0; t < NT; ++t)
      b[t] = *(const bf16x8*)(w1tf + ((size_t)(kc * 13 + NT0 + t) * 64 + lane) * 8);
    bf16x8 a[4];
    #pragma unroll
    for (int mi = 0; mi < 4; ++mi)
      a[mi] = *(const bf16x8*)(featg + ((size_t)((blk4 + mi) * 22 + kc) * 64 + sw) * 8);
    #pragma unroll
    for (int mi = 0; mi < 4; ++mi)
      #pragma unroll
      for (int t = 0; t < NT; ++t)
        acc[mi][t] = __builtin_amdgcn_mfma_f32_16x16x32_bf16(a[mi], b[t], acc[mi][t], 0, 0, 0);
  }

  #pragma unroll
  for (int t = 0; t < NT; ++t) {
    const int n = (NT0 + t) * 16 + ln;
    if (n < HID) {
      const float bias = b1[n];
      const int kc2 = n >> 5, qd2 = (n >> 3) & 3, j2 = n & 7, c2 = kc2 & 7;
      #pragma unroll
      for (int mi = 0; mi < 4; ++mi)
        #pragma unroll
        for (int rr = 0; rr < 4; ++rr) {
          const int m = qd * 4 + rr;
          float h = fmaxf(acc[mi][t][rr] + bias, 0.f);
          __hip_bfloat16 hb = __float2bfloat16(h);
          hidA[mi * 3584 + (kc2 * 64 + qd2 * 16 + (m ^ c2)) * 8 + j2] =
              __builtin_bit_cast(unsigned short, hb);
        }
    }
  }
}

__global__ __launch_bounds__(256, 4) void gemmk(
    const unsigned short* __restrict__ featg, const unsigned short* __restrict__ w1tf,
    const unsigned short* __restrict__ w2f, const float* __restrict__ b1,
    const float* __restrict__ b2, float* __restrict__ out) {
  __shared__ __align__(16) unsigned short hidA[4 * 7 * 64 * 8];  // 28,672 B
  const int tid  = threadIdx.x;
  const int wave = tid >> 6;
  const int lane = tid & 63;

  // zero hid K-pad (k=200..223): 4 tiles x 16 rows x 12 dwords
  for (int i = tid; i < 768; i += 256) {
    int mi = i / 192, r = i - mi * 192, m = r / 12, d = r - m * 12;
    *(unsigned int*)fslot(hidA + mi * 3584, m, 200 + 2 * d) = 0u;
  }

  const int blk4 = blockIdx.x * 4;
  switch (wave) {
    case 0:  gemmB_slice<0, 4>(featg, w1tf, b1, hidA, lane, blk4); break;
    case 1:  gemmB_slice<4, 3>(featg, w1tf, b1, hidA, lane, blk4); break;
    case 2:  gemmB_slice<7, 3>(featg, w1tf, b1, hidA, lane, blk4); break;
    default: gemmB_slice<10, 3>(featg, w1tf, b1, hidA, lane, blk4); break;
  }
  __syncthreads();   // hidA complete (incl. pads)

  // GEMM2: wave w handles m-tile w. 7 MFMA over K=224.
  const int ln = lane & 15, qd = lane >> 4;
  f32x4 acc2 = (f32x4){0.f, 0.f, 0.f, 0.f};
  #pragma unroll
  for (int kc = 0; kc < 7; ++kc) {
    bf16x8 a = *(const bf16x8*)&hidA[wave * 3584 + (kc * 64 + (lane ^ (kc & 7))) * 8];
    bf16x8 b = *(const bf16x8*)(w2f + ((size_t)kc * 64 + lane) * 8);
    acc2 = __builtin_amdgcn_mfma_f32_16x16x32_bf16(a, b, acc2, 0, 0, 0);
  }
  if (ln < NCLS) {
    const float bb = b2[ln];
    #pragma unroll
    for (int rr = 0; rr < 4; ++rr) {
      out[((size_t)(blk4 + wave) * 16 + qd * 4 + rr) * NCLS + ln] = acc2[rr] + bb;
    }
  }
}

// ---------------------------------------------------------------------------
// Fallback (ws too small for featg): R1 single fused kernel, 147us measured.
// ---------------------------------------------------------------------------
template<int NT0, int NT>
__device__ __forceinline__ void gemm1_slice(
    const unsigned short* featA, const unsigned short* __restrict__ w1tf,
    const float* __restrict__ b1, unsigned short* hidA, int lane) {
  const int ln = lane & 15, qd = lane >> 4;
  f32x4 acc[NT];
  #pragma unroll
  for (int t = 0; t < NT; ++t) acc[t] = (f32x4){0.f, 0.f, 0.f, 0.f};
  for (int kc = 0; kc < 22; ++kc) {
    bf16x8 a = *(const bf16x8*)&featA[(kc * 64 + (lane ^ (kc & 7))) * 8];
    #pragma unroll
    for (int t = 0; t < NT; ++t) {
      bf16x8 b = *(const bf16x8*)(w1tf + ((size_t)(kc * 13 + NT0 + t) * 64 + lane) * 8);
      acc[t] = __builtin_amdgcn_mfma_f32_16x16x32_bf16(a, b, acc[t], 0, 0, 0);
    }
  }
  #pragma unroll
  for (int t = 0; t < NT; ++t) {
    const int n = (NT0 + t) * 16 + ln;
    if (n < HID) {
      const float bias = b1[n];
      const int kc2 = n >> 5, qd2 = (n >> 3) & 3, j2 = n & 7, c2 = kc2 & 7;
      #pragma unroll
      for (int rr = 0; rr < 4; ++rr) {
        const int m = qd * 4 + rr;
        float h = fmaxf(acc[t][rr] + bias, 0.f);
        __hip_bfloat16 hb = __float2bfloat16(h);
        hidA[(kc2 * 64 + qd2 * 16 + (m ^ c2)) * 8 + j2] =
            __builtin_bit_cast(unsigned short, hb);
      }
    }
  }
}

__global__ __launch_bounds__(256, 5) void fused2(
    const float* __restrict__ x, const float* __restrict__ cwp,
    const unsigned short* __restrict__ w1tf, const unsigned short* __restrict__ w2f,
    const float* __restrict__ b1, const float* __restrict__ b2,
    float* __restrict__ out) {
  __shared__ __align__(16) unsigned short featA[22 * 64 * 8];
  __shared__ __align__(16) unsigned short hidA [ 7 * 64 * 8];
  const int tid  = threadIdx.x;
  const int wave = tid >> 6;
  const int lane = tid & 63;

  for (int i = tid; i < MT * 14; i += 256) {
    int m = i / 14, d = i - m * 14;
    *(unsigned int*)fslot(featA, m, 676 + 2 * d) = 0u;
  }
  for (int i = tid; i < MT * 12; i += 256) {
    int m = i / 12, d = i - m * 12;
    *(unsigned int*)fslot(hidA, m, 200 + 2 * d) = 0u;
  }

  float cw[9];
  #pragma unroll
  for (int t = 0; t < 9; ++t) cw[t] = cwp[t];

  const float* xb = x + (size_t)blockIdx.x * (MT * 784);
  for (int t0 = 0; t0 < 364; t0 += 64) {
    const int t = t0 + lane;
    if (t < 364) {
      const int p   = (t * 721) >> 16;
      const int r91 = t - 91 * p;
      const int iq  = (r91 * 9363) >> 16;
      const int jc  = r91 - 7 * iq;
      const int m   = 4 * p + wave;
      const float* xw = xb + m * 784;
      float in[4][6];
      const int c2 = (jc < 6) ? 4 : 2;
      #pragma unroll
      for (int rr = 0; rr < 4; ++rr) {
        const float* rp = xw + (2 * iq + rr) * HW + 4 * jc;
        const float4 v = *(const float4*)rp;
        const float2 u = *(const float2*)(rp + c2);
        in[rr][0] = v.x; in[rr][1] = v.y; in[rr][2] = v.z; in[rr][3] = v.w;
        in[rr][4] = u.x; in[rr][5] = u.y;
      }
      float o[2][4];
      #pragma unroll
      for (int dr = 0; dr < 2; ++dr)
        #pragma unroll
        for (int dc = 0; dc < 4; ++dc) {
          float s = 0.f;
          #pragma unroll
          for (int di = 0; di < 3; ++di)
            #pragma unroll
            for (int dj = 0; dj < 3; ++dj)
              s += cw[di * 3 + dj] * in[dr + di][dc + dj];
          o[dr][dc] = s;
        }
      const int k0 = 52 * iq + 4 * jc;
      if (jc < 6) {
        *(uint2*)fslot(featA, m, k0) =
            make_uint2(pk2(o[0][0], o[0][1]), pk2(o[0][2], o[0][3]));
        *(unsigned int*)fslot(featA, m, k0 + OHW)     = pk2(o[1][0], o[1][1]);
        *(unsigned int*)fslot(featA, m, k0 + OHW + 2) = pk2(o[1][2], o[1][3]);
      } else {
        *(unsigned int*)fslot(featA, m, k0)       = pk2(o[0][0], o[0][1]);
        *(unsigned int*)fslot(featA, m, k0 + OHW) = pk2(o[1][0], o[1][1]);
      }
    }
  }
  __syncthreads();

  switch (wave) {
    case 0:  gemm1_slice<0, 4>(featA, w1tf, b1, hidA, lane); break;
    case 1:  gemm1_slice<4, 3>(featA, w1tf, b1, hidA, lane); break;
    case 2:  gemm1_slice<7, 3>(featA, w1tf, b1, hidA, lane); break;
    default: gemm1_slice<10, 3>(featA, w1tf, b1, hidA, lane); break;
  }
  __syncthreads();

  if (wave == 0) {
    const int ln = lane & 15, qd = lane >> 4;
    f32x4 acc2 = (f32x4){0.f, 0.f, 0.f, 0.f};
    #pragma unroll
    for (int kc = 0; kc < 7; ++kc) {
      bf16x8 a = *(const bf16x8*)&hidA[(kc * 64 + (lane ^ (kc & 7))) * 8];
      bf16x8 b = *(const bf16x8*)(w2f + ((size_t)kc * 64 + lane) * 8);
      acc2 = __builtin_amdgcn_mfma_f32_16x16x32_bf16(a, b, acc2, 0, 0, 0);
    }
    if (ln < NCLS) {
      const float bb = b2[ln];
      #pragma unroll
      for (int rr = 0; rr < 4; ++rr) {
        out[((size_t)blockIdx.x * MT + qd * 4 + rr) * NCLS + ln] = acc2[rr] + bb;
      }
    }
  }
}

extern "C" void kernel_launch(void* const* d_in, const int* in_sizes, int n_in,
                              void* d_out, int out_size, void* d_ws, size_t ws_size,
                              hipStream_t stream) {
  const float* x  = (const float*)d_in[0];
  const float* cw = (const float*)d_in[1];
  const float* w1 = (const float*)d_in[2];
  const float* b1 = (const float*)d_in[3];
  const float* w2 = (const float*)d_in[4];
  const float* b2 = (const float*)d_in[5];
  float* out = (float*)d_out;

  unsigned short* w1tf = (unsigned short*)d_ws;                       // 292,864 B
  unsigned short* w2f  = (unsigned short*)((char*)d_ws + 294912);     //   7,168 B
  unsigned short* featg = (unsigned short*)((char*)d_ws + 307200);    // 92,274,688 B

  hipLaunchKernelGGL(prep_w1tf, dim3((22 * 13 * 64 + 255) / 256), dim3(256), 0, stream,
                     w1, w1tf);
  hipLaunchKernelGGL(prep_w2f, dim3(2), dim3(256), 0, stream, w2, w2f);

  const size_t need = 307200 + (size_t)NBLOCKS * 22528;
  if (ws_size >= need) {
    hipLaunchKernelGGL(convk, dim3(NBLOCKS), dim3(256), 0, stream, x, cw, featg);
    hipLaunchKernelGGL(gemmk, dim3(GBLOCKS), dim3(256), 0, stream,
                       featg, w1tf, w2f, b1, b2, out);
  } else {
    hipLaunchKernelGGL(fused2, dim3(NBLOCKS), dim3(256), 0, stream,
                       x, cw, w1tf, w2f, b1, b2, out);
  }
}